// Round 11
// baseline (101.407 us; speedup 1.0000x reference)
//
#include <hip/hip_runtime.h>
#include <hip/hip_bf16.h>
#include <stdint.h>

// Problem constants (from reference): B=32, NB=64, PL=20, FD=4096, H=1024
#define B_   32
#define NB_  64
#define PL_  20
#define FD_  4096
#define H_   1024
#define M_   (B_ * NB_)   // 2048 regions

typedef short bf16x8 __attribute__((ext_vector_type(8)));
typedef float f32x4  __attribute__((ext_vector_type(4)));

// f32 -> bf16 round-to-nearest-even
__device__ __forceinline__ ushort f2bf(float f) {
    uint32_t u = __builtin_bit_cast(uint32_t, f);
    u += 0x7fffu + ((u >> 16) & 1u);
    return (ushort)(u >> 16);
}

// ---------------------------------------------------------------------------
// Fused prep kernel (block-range dispatch) — unchanged (verified R4-R10).
// ---------------------------------------------------------------------------
__global__ __launch_bounds__(256) void prep_kernel(
    const float* __restrict__ lang, const int* __restrict__ plen,
    ushort* __restrict__ pooled,
    const float* __restrict__ vision, ushort* __restrict__ visionb,
    const float* __restrict__ Wv, ushort* __restrict__ WvT,
    const float* __restrict__ Wl, ushort* __restrict__ WlT)
{
    __shared__ float tile[32][33];   // transpose staging (+1 pad)
    int blk = blockIdx.x;
    int tid = threadIdx.x;

    if (blk < M_) {
        int r = blk;
        int h = tid << 2;
        const float* base = lang + (size_t)r * (PL_ * H_) + h;
        float sx = 0.f, sy = 0.f, sz = 0.f, sw = 0.f;
#pragma unroll
        for (int p = 0; p < PL_; ++p) {
            float4 v = *(const float4*)(base + (size_t)p * H_);
            sx += v.x; sy += v.y; sz += v.z; sw += v.w;
        }
        float inv = 1.0f / (float)plen[r];
        ushort4 o = make_ushort4(f2bf(sx * inv), f2bf(sy * inv),
                                 f2bf(sz * inv), f2bf(sw * inv));
        *(ushort4*)(pooled + (size_t)r * H_ + h) = o;
    } else if (blk < M_ + 8192) {
        int i = (blk - M_) * 256 + tid;        // i < 2048*4096/4
        float4 v = ((const float4*)vision)[i];
        ushort4 o = make_ushort4(f2bf(v.x), f2bf(v.y), f2bf(v.z), f2bf(v.w));
        ((ushort4*)visionb)[i] = o;
    } else {
        const float* W; ushort* Wt; int K, b;
        if (blk < M_ + 8192 + 4096) { W = Wv; Wt = WvT; K = FD_; b = blk - (M_ + 8192); }
        else                        { W = Wl; Wt = WlT; K = H_;  b = blk - (M_ + 8192 + 4096); }
        int n0 = (b & 31) * 32, k0 = (b >> 5) * 32;
        int tx = tid & 31, ty = tid >> 5;      // ty in 0..7
#pragma unroll
        for (int i = 0; i < 32; i += 8)
            tile[ty + i][tx] = W[(size_t)(k0 + ty + i) * H_ + n0 + tx];
        __syncthreads();
#pragma unroll
        for (int i = 0; i < 32; i += 8)
            Wt[(size_t)(n0 + ty + i) * K + k0 + tx] = f2bf(tile[tx][ty + i]);
    }
}

// ---------------------------------------------------------------------------
// Dual bf16 GEMM-BT, NBUF=3 / BK=32 unpinned pipeline (T3+T4) + T2 swizzle:
//   C[M][N] = A[M][K] * Bt[N][K]^T (+ bias)
// Grid: 512 blocks x 256 threads (4 waves 2x2, per-wave 64x64 = acc[4][4]).
//   wgid [0,384)  : vision GEMM (K=4096, 128 BK32-steps) split-K 3-way
//                   {43,43,42}; partials via atomicAdd (C pre-zeroed);
//                   bias added by split ks==0.
//   wgid [384,512): language GEMM (K=1024, 32 steps), plain stores + bias.
// 2 blocks/CU (48 KB LDS each) -> 8 waves/CU + cross-block async overlap.
// NBUF=3 removes the R10 read-drain pin: stage(kt+2) writes buf[(kt-1)%3],
// whose reads are complete before any wave passes barrier(kt) (MFMA operand
// dependency forces read completion before MFMA issue, which precedes the
// barrier). => ONE barrier per K-step, NO lgkmcnt(0) pin, NO second barrier;
// compiler interleaves ds_read/MFMA with fine-grained lgkmcnt itself.
// Pipeline: prologue stage(0),stage(1); iter kt: vmcnt(4) [last: 0] ->
//   s_barrier -> stage(kt+2) -> ds_read frags(kt) -> 16 MFMA.
// (4 gload_lds issues per tile per thread -> steady vmcnt(4).)
// Swizzle (rule 21, BK=32 geometry): row = 64 B; linear LDS dest, global
// source col ^= ((row&3)<<4); read col applies the same XOR (row&3 == lx&3).
// XCD pinning: wg%8 == y -> B-panel L2-resident per XCD.
// ---------------------------------------------------------------------------
#define BM 128
#define BN 128
#define BK 32

__device__ __forceinline__ void async16(const void* g, void* l) {
    __builtin_amdgcn_global_load_lds(
        (const __attribute__((address_space(1))) void*)g,
        (__attribute__((address_space(3))) void*)l, 16, 0, 0);
}

// Stage one 128x32 A-tile (8 KB) + 128x32 B-tile (8 KB), bf16.
// 256 threads x 16B x 2 issues per matrix (4 loads/thread/tile).
__device__ __forceinline__ void stage_tile(
    const char* Ag, const char* Bg, size_t Kb, size_t ko,
    char* AsB, char* BsB, int tid)
{
#pragma unroll
    for (int j = 0; j < 2; ++j) {
        int off = j * 4096 + tid * 16;                  // linear LDS byte off
        int row = off >> 6;                             // 64 B per row
        int cbl = off & 63;                             // LDS byte col
        int cbg = cbl ^ ((row & 3) << 4);               // swizzled global col
        async16(Ag + (size_t)row * Kb + ko + cbg, AsB + off);
        async16(Bg + (size_t)row * Kb + ko + cbg, BsB + off);
    }
}

__global__ __launch_bounds__(256) void gemm_bt_dual(
    const ushort* __restrict__ A1, const ushort* __restrict__ Bt1,
    const float* __restrict__ bias1, float* __restrict__ C1,
    const ushort* __restrict__ A2, const ushort* __restrict__ Bt2,
    const float* __restrict__ bias2, float* __restrict__ C2)
{
    __shared__ ushort As[3][BM * BK];   // 3 x 8 KB
    __shared__ ushort Bs[3][BN * BK];   // 3 x 8 KB

    int wg = blockIdx.x;
    bool isV = wg < 384;
    int w, ks, nk, k0s;
    if (isV) {
        ks = wg >> 7;                   // 0..2
        w  = wg & 127;
        nk  = (ks == 2) ? 42 : 43;      // 43+43+42 = 128 K-steps
        k0s = ks * 43;
    } else {
        ks = 0; w = wg - 384; nk = 32; k0s = 0;
    }
    int y = w & 7, x = w >> 3;          // XCD == wg%8 == y (round-robin)

    const ushort* A   = isV ? A1 : A2;
    const ushort* Bt  = isV ? Bt1 : Bt2;
    const float* bias = isV ? bias1 : bias2;
    float* C          = isV ? C1 : C2;
    int K             = isV ? FD_ : H_;

    const int N = H_;
    int tid  = threadIdx.x;
    int wave = tid >> 6, lane = tid & 63;
    int lx = lane & 15, lz = lane >> 4;
    int wr = wave >> 1, wc = wave & 1;  // 2x2 waves, each owns 64x64
    int row0 = x * BM;
    int col0 = y * BN;

    size_t Kb = (size_t)K * 2;          // bytes per logical row

    const char* Ag = (const char*)A  + (size_t)row0 * Kb;
    const char* Bg = (const char*)Bt + (size_t)col0 * Kb;

    int sw = (lx & 3) << 4;             // read-side swizzle XOR (BK=32)

    f32x4 acc[4][4] = {};

    // prologue: stage tiles 0,1 (8 outstanding loads per thread)
    stage_tile(Ag, Bg, Kb, (size_t)k0s * 64,       (char*)As[0], (char*)Bs[0], tid);
    stage_tile(Ag, Bg, Kb, (size_t)(k0s + 1) * 64, (char*)As[1], (char*)Bs[1], tid);

    int cur = 0;                        // buffer holding tile kt
    for (int kt = 0; kt < nk; ++kt) {
        if (kt < nk - 1) asm volatile("s_waitcnt vmcnt(4)" ::: "memory");
        else             asm volatile("s_waitcnt vmcnt(0)" ::: "memory");
        __builtin_amdgcn_s_barrier();   // stage(kt) visible; reads of kt-1
                                        // complete in all waves (see header)

        int stg = cur + 2; if (stg >= 3) stg -= 3;   // == (kt+2)%3
        if (kt + 2 < nk)
            stage_tile(Ag, Bg, Kb, (size_t)(k0s + kt + 2) * 64,
                       (char*)As[stg], (char*)Bs[stg], tid);

        const char* Ab = (const char*)As[cur];
        const char* Bb = (const char*)Bs[cur];
        bf16x8 af[4], bfr[4];
#pragma unroll
        for (int m = 0; m < 4; ++m)
            af[m] = *(const bf16x8*)(Ab +
                (wr * 64 + m * 16 + lx) * 64 + ((lz * 16) ^ sw));
#pragma unroll
        for (int n = 0; n < 4; ++n)
            bfr[n] = *(const bf16x8*)(Bb +
                (wc * 64 + n * 16 + lx) * 64 + ((lz * 16) ^ sw));
#pragma unroll
        for (int m = 0; m < 4; ++m)
#pragma unroll
            for (int n = 0; n < 4; ++n)
                acc[m][n] = __builtin_amdgcn_mfma_f32_16x16x32_bf16(
                    af[m], bfr[n], acc[m][n], 0, 0, 0);

        cur = (cur + 1 == 3) ? 0 : cur + 1;
    }

    // Epilogue. D frag: col = lane&15, row = (lane>>4)*4 + reg  [verified map]
#pragma unroll
    for (int m = 0; m < 4; ++m) {
        int row = row0 + wr * 64 + m * 16 + lz * 4;
#pragma unroll
        for (int n = 0; n < 4; ++n) {
            int col = col0 + wc * 64 + n * 16 + lx;
            float bb = (ks == 0) ? bias[col] : 0.f;
            if (isV) {
#pragma unroll
                for (int r = 0; r < 4; ++r)
                    atomicAdd(&C[(size_t)(row + r) * N + col],
                              acc[m][n][r] + bb);
            } else {
#pragma unroll
                for (int r = 0; r < 4; ++r)
                    C[(size_t)(row + r) * N + col] = acc[m][n][r] + bb;
            }
        }
    }
}

// ---------------------------------------------------------------------------
extern "C" void kernel_launch(void* const* d_in, const int* in_sizes, int n_in,
                              void* d_out, int out_size, void* d_ws, size_t ws_size,
                              hipStream_t stream) {
    const float* vision   = (const float*)d_in[0];   // [2048, 4096]
    const float* language = (const float*)d_in[1];   // [2048, 20, 1024]
    const int*   plen     = (const int*)d_in[2];     // [2048]
    const float* Wv       = (const float*)d_in[3];   // [4096, 1024]
    const float* bv       = (const float*)d_in[4];   // [1024]
    const float* Wl       = (const float*)d_in[5];   // [1024, 1024]
    const float* bl       = (const float*)d_in[6];   // [1024]

    float* out      = (float*)d_out;
    float* lang_map = out;                        // output 0: [2048,1024]
    float* vis_map  = out + (size_t)M_ * H_;      // output 1: [2048,1024]

    char* ws = (char*)d_ws;
    ushort* pooled  = (ushort*)(ws);                   // 4 MB  [2048][1024]
    ushort* visionb = (ushort*)(ws + (4u  << 20));     // 16 MB [2048][4096]
    ushort* WvT     = (ushort*)(ws + (20u << 20));     // 8 MB  [1024][4096]
    ushort* WlT     = (ushort*)(ws + (28u << 20));     // 2 MB  [1024][1024]

    // vision output accumulated via atomics -> zero it every launch
    // (replay-safe: each replay re-zeroes before accumulating)
    hipMemsetAsync(vis_map, 0, (size_t)M_ * H_ * sizeof(float), stream);

    // prep: 2048 pool + 8192 convert + 4096 WvT + 1024 WlT = 15360 blocks
    hipLaunchKernelGGL(prep_kernel, dim3(15360), dim3(256), 0, stream,
                       language, plen, pooled, vision, visionb,
                       Wv, WvT, Wl, WlT);
    // GEMM: 512 blocks x 256 threads (384 vision split-K + 128 language)
    hipLaunchKernelGGL(gemm_bt_dual, dim3(512), dim3(256), 0, stream,
                       visionb, WvT, bv, vis_map,
                       pooled,  WlT, bl, lang_map);
}

// Round 13
// 100.573 us; speedup vs baseline: 1.0083x; 1.0083x over previous
//
#include <hip/hip_runtime.h>
#include <hip/hip_bf16.h>
#include <stdint.h>

// Problem constants (from reference): B=32, NB=64, PL=20, FD=4096, H=1024
#define B_   32
#define NB_  64
#define PL_  20
#define FD_  4096
#define H_   1024
#define M_   (B_ * NB_)   // 2048 regions

typedef short bf16x8 __attribute__((ext_vector_type(8)));
typedef float f32x4  __attribute__((ext_vector_type(4)));

// f32 -> bf16 round-to-nearest-even
__device__ __forceinline__ ushort f2bf(float f) {
    uint32_t u = __builtin_bit_cast(uint32_t, f);
    u += 0x7fffu + ((u >> 16) & 1u);
    return (ushort)(u >> 16);
}

// ---------------------------------------------------------------------------
// Launch A: small prep (vision GEMM's only dependencies):
//   blocks [0, 8192)      : vision f32 -> bf16 (1024 elems/block)
//   blocks [8192, 12288)  : WvT[n][k] = bf16(Wv[k][n])  (32x32 tiles)
//   blocks [12288, 13312) : WlT[n][k] = bf16(Wl[k][n])
// ---------------------------------------------------------------------------
__global__ __launch_bounds__(256) void prep_small(
    const float* __restrict__ vision, ushort* __restrict__ visionb,
    const float* __restrict__ Wv, ushort* __restrict__ WvT,
    const float* __restrict__ Wl, ushort* __restrict__ WlT)
{
    __shared__ float tile[32][33];
    int blk = blockIdx.x, tid = threadIdx.x;
    if (blk < 8192) {
        int i = blk * 256 + tid;               // < 2048*4096/4
        float4 v = ((const float4*)vision)[i];
        ushort4 o = make_ushort4(f2bf(v.x), f2bf(v.y), f2bf(v.z), f2bf(v.w));
        ((ushort4*)visionb)[i] = o;
    } else {
        const float* W; ushort* Wt; int K, b;
        if (blk < 12288) { W = Wv; Wt = WvT; K = FD_; b = blk - 8192; }
        else             { W = Wl; Wt = WlT; K = H_;  b = blk - 12288; }
        int n0 = (b & 31) * 32, k0 = (b >> 5) * 32;
        int tx = tid & 31, ty = tid >> 5;      // ty in 0..7
#pragma unroll
        for (int i = 0; i < 32; i += 8)
            tile[ty + i][tx] = W[(size_t)(k0 + ty + i) * H_ + n0 + tx];
        __syncthreads();
#pragma unroll
        for (int i = 0; i < 32; i += 8)
            Wt[(size_t)(n0 + ty + i) * K + k0 + tx] = f2bf(tile[tx][ty + i]);
    }
}

// ---------------------------------------------------------------------------
// R10-proven GEMM core (BK=64, NBUF=2, counted vmcnt, T2 involution swizzle).
// C-partial accumulated in acc[4][4]; per-wave 64x64 (2x2 waves, 256 thr).
// ---------------------------------------------------------------------------
#define BM 128
#define BN 128
#define BK 64

__device__ __forceinline__ void async16(const void* g, void* l) {
    __builtin_amdgcn_global_load_lds(
        (const __attribute__((address_space(1))) void*)g,
        (__attribute__((address_space(3))) void*)l, 16, 0, 0);
}

// Stage one 128x64 A-tile (16 KB) + 128x64 B-tile (16 KB), bf16.
// 256 threads x 16B x 4 issues per matrix (8 loads/thread/tile).
__device__ __forceinline__ void stage_tile(
    const char* Ag, const char* Bg, size_t Kb, size_t ko,
    char* AsB, char* BsB, int tid)
{
#pragma unroll
    for (int j = 0; j < 4; ++j) {
        int off = j * 4096 + tid * 16;                  // linear LDS byte off
        int row = off >> 7;                             // 128 B per row
        int cbl = off & 127;                            // LDS byte col
        int cbg = cbl ^ ((row & 7) << 4);               // swizzled global col
        async16(Ag + (size_t)row * Kb + ko + cbg, AsB + off);
        async16(Bg + (size_t)row * Kb + ko + cbg, BsB + off);
    }
}

// K-loop: vmcnt(8) -> barrier -> ds_read -> lgkmcnt(0) -> barrier ->
// stage(kt+2) -> 32 MFMA.  (R10 structure, measured best.)
__device__ __forceinline__ void gemm_bt_core(
    const char* Ag, const char* Bg, size_t Kb, int k0s, int nk,
    ushort (*As)[BM * BK], ushort (*Bs)[BN * BK],
    int tid, int wr, int wc, int lx, int lz, f32x4 acc[4][4])
{
    int sw = (lx & 7) << 4;             // read-side swizzle XOR

    stage_tile(Ag, Bg, Kb, (size_t)k0s * 128,       (char*)As[0], (char*)Bs[0], tid);
    stage_tile(Ag, Bg, Kb, (size_t)(k0s + 1) * 128, (char*)As[1], (char*)Bs[1], tid);

    for (int kt = 0; kt < nk; ++kt) {
        if (kt < nk - 1) asm volatile("s_waitcnt vmcnt(8)" ::: "memory");
        else             asm volatile("s_waitcnt vmcnt(0)" ::: "memory");
        __builtin_amdgcn_s_barrier();   // stage(kt) visible

        const char* Ab = (const char*)As[kt & 1];
        const char* Bb = (const char*)Bs[kt & 1];
        bf16x8 af[2][4], bfr[2][4];
#pragma unroll
        for (int kk = 0; kk < 2; ++kk) {
#pragma unroll
            for (int m = 0; m < 4; ++m)
                af[kk][m] = *(const bf16x8*)(Ab +
                    (wr * 64 + m * 16 + lx) * 128 + ((kk * 64 + lz * 16) ^ sw));
#pragma unroll
            for (int n = 0; n < 4; ++n)
                bfr[kk][n] = *(const bf16x8*)(Bb +
                    (wc * 64 + n * 16 + lx) * 128 + ((kk * 64 + lz * 16) ^ sw));
        }
        asm volatile("s_waitcnt lgkmcnt(0)" ::: "memory"); // reads complete
        __builtin_amdgcn_s_barrier();   // buffer kt reusable block-wide

        if (kt + 2 < nk)
            stage_tile(Ag, Bg, Kb, (size_t)(k0s + kt + 2) * 128,
                       (char*)As[kt & 1], (char*)Bs[kt & 1], tid);

#pragma unroll
        for (int kk = 0; kk < 2; ++kk)
#pragma unroll
            for (int m = 0; m < 4; ++m)
#pragma unroll
                for (int n = 0; n < 4; ++n)
                    acc[m][n] = __builtin_amdgcn_mfma_f32_16x16x32_bf16(
                        af[kk][m], bfr[kk][n], acc[m][n], 0, 0, 0);
    }
}

// Shared epilogue: atomicAdd partials (C pre-zeroed); bias on split ks==0.
// D frag: col = lane&15, row = (lane>>4)*4 + reg  [verified map]
__device__ __forceinline__ void gemm_epilogue(
    float* C, const float* bias, int ks, int row0, int col0,
    int wr, int wc, int lx, int lz, f32x4 acc[4][4])
{
#pragma unroll
    for (int m = 0; m < 4; ++m) {
        int row = row0 + wr * 64 + m * 16 + lz * 4;
#pragma unroll
        for (int n = 0; n < 4; ++n) {
            int col = col0 + wc * 64 + n * 16 + lx;
            float bb = (ks == 0) ? bias[col] : 0.f;
#pragma unroll
            for (int r = 0; r < 4; ++r)
                atomicAdd(&C[(size_t)(row + r) * H_ + col],
                          acc[m][n][r] + bb);
        }
    }
}

// ---------------------------------------------------------------------------
// Launch B: fused vision-GEMM + language-pool (disjoint resources overlap):
//   blocks [0, 384)    : vision GEMM (K=4096) split-K 3-way {22,21,21},
//                        XCD-pinned (wg%8 == y), 2 blocks/CU (64 KB LDS).
//   blocks [384, 2432) : pool region r = wg-384 (pure HBM streaming — fills
//                        the CU slots / HBM bandwidth the GEMM doesn't use).
// ---------------------------------------------------------------------------
__global__ __launch_bounds__(256) void gemm_vision_pool(
    const ushort* __restrict__ Av, const ushort* __restrict__ Btv,
    const float* __restrict__ bv, float* __restrict__ Cv,
    const float* __restrict__ lang, const int* __restrict__ plen,
    ushort* __restrict__ pooled)
{
    __shared__ ushort As[2][BM * BK];   // 2 x 16 KB
    __shared__ ushort Bs[2][BN * BK];   // 2 x 16 KB

    int wg = blockIdx.x, tid = threadIdx.x;
    if (wg < 384) {
        int ks = wg >> 7;               // 0..2
        int w  = wg & 127;
        int nk  = (ks == 0) ? 22 : 21;  // 22+21+21 = 64 K-steps
        int k0s = (ks == 0) ? 0 : (22 + (ks - 1) * 21);
        int y = w & 7, x = w >> 3;      // XCD == wg%8 == y

        int wave = tid >> 6, lane = tid & 63;
        int lx = lane & 15, lz = lane >> 4;
        int wr = wave >> 1, wc = wave & 1;

        size_t Kb = (size_t)FD_ * 2;
        const char* Ag = (const char*)Av  + (size_t)(x * BM) * Kb;
        const char* Bg = (const char*)Btv + (size_t)(y * BN) * Kb;

        f32x4 acc[4][4] = {};
        gemm_bt_core(Ag, Bg, Kb, k0s, nk, As, Bs, tid, wr, wc, lx, lz, acc);
        gemm_epilogue(Cv, bv, ks, x * BM, y * BN, wr, wc, lx, lz, acc);
    } else {
        // ---- pool: region r, thread covers 4 h's ----
        int r = wg - 384;
        int h = tid << 2;
        const float* base = lang + (size_t)r * (PL_ * H_) + h;
        float sx = 0.f, sy = 0.f, sz = 0.f, sw = 0.f;
#pragma unroll
        for (int p = 0; p < PL_; ++p) {
            float4 v = *(const float4*)(base + (size_t)p * H_);
            sx += v.x; sy += v.y; sz += v.z; sw += v.w;
        }
        float inv = 1.0f / (float)plen[r];
        ushort4 o = make_ushort4(f2bf(sx * inv), f2bf(sy * inv),
                                 f2bf(sz * inv), f2bf(sw * inv));
        *(ushort4*)(pooled + (size_t)r * H_ + h) = o;
    }
}

// ---------------------------------------------------------------------------
// Launch C: language GEMM (K=1024), split-K 2-way {8,8}, 256 blocks.
// ---------------------------------------------------------------------------
__global__ __launch_bounds__(256) void gemm_lang(
    const ushort* __restrict__ Al, const ushort* __restrict__ Btl,
    const float* __restrict__ bl, float* __restrict__ Cl)
{
    __shared__ ushort As[2][BM * BK];
    __shared__ ushort Bs[2][BN * BK];

    int wg = blockIdx.x, tid = threadIdx.x;
    int ks = wg >> 7;                   // 0..1
    int w  = wg & 127;
    int nk = 8, k0s = ks * 8;           // 8+8 = 16 K-steps
    int y = w & 7, x = w >> 3;

    int wave = tid >> 6, lane = tid & 63;
    int lx = lane & 15, lz = lane >> 4;
    int wr = wave >> 1, wc = wave & 1;

    size_t Kb = (size_t)H_ * 2;
    const char* Ag = (const char*)Al  + (size_t)(x * BM) * Kb;
    const char* Bg = (const char*)Btl + (size_t)(y * BN) * Kb;

    f32x4 acc[4][4] = {};
    gemm_bt_core(Ag, Bg, Kb, k0s, nk, As, Bs, tid, wr, wc, lx, lz, acc);
    gemm_epilogue(Cl, bl, ks, x * BM, y * BN, wr, wc, lx, lz, acc);
}

// ---------------------------------------------------------------------------
extern "C" void kernel_launch(void* const* d_in, const int* in_sizes, int n_in,
                              void* d_out, int out_size, void* d_ws, size_t ws_size,
                              hipStream_t stream) {
    const float* vision   = (const float*)d_in[0];   // [2048, 4096]
    const float* language = (const float*)d_in[1];   // [2048, 20, 1024]
    const int*   plen     = (const int*)d_in[2];     // [2048]
    const float* Wv       = (const float*)d_in[3];   // [4096, 1024]
    const float* bv       = (const float*)d_in[4];   // [1024]
    const float* Wl       = (const float*)d_in[5];   // [1024, 1024]
    const float* bl       = (const float*)d_in[6];   // [1024]

    float* out      = (float*)d_out;
    float* lang_map = out;                        // output 0: [2048,1024]
    float* vis_map  = out + (size_t)M_ * H_;      // output 1: [2048,1024]

    char* ws = (char*)d_ws;
    ushort* pooled  = (ushort*)(ws);                   // 4 MB  [2048][1024]
    ushort* visionb = (ushort*)(ws + (4u  << 20));     // 16 MB [2048][4096]
    ushort* WvT     = (ushort*)(ws + (20u << 20));     // 8 MB  [1024][4096]
    ushort* WlT     = (ushort*)(ws + (28u << 20));     // 2 MB  [1024][1024]

    // Both outputs accumulated via atomics -> zero whole output each launch
    // (replay-safe: every replay re-zeroes before accumulating).
    hipMemsetAsync(out, 0, (size_t)2 * M_ * H_ * sizeof(float), stream);

    // A: vision cvt + W transposes (vision GEMM deps only), ~85 MB
    hipLaunchKernelGGL(prep_small, dim3(13312), dim3(256), 0, stream,
                       vision, visionb, Wv, WvT, Wl, WlT);
    // B: vision GEMM (384 blocks, dispatched first) ∥ language pool (2048)
    hipLaunchKernelGGL(gemm_vision_pool, dim3(2432), dim3(256), 0, stream,
                       visionb, WvT, bv, vis_map,
                       language, plen, pooled);
    // C: language GEMM (256 blocks, split-K x2)
    hipLaunchKernelGGL(gemm_lang, dim3(256), dim3(256), 0, stream,
                       pooled, WlT, bl, lang_map);
}